// Round 12
// baseline (1571.451 us; speedup 1.0000x reference)
//
#include <hip/hip_runtime.h>
#include <hip/hip_fp16.h>

// GIN (5 layers) + BN + pool + MLP head, fused pipeline for MI355X. Round 14.
// R13 (cooperative mega-kernel) FAILED correctness: grid.sync + threadfence
// did not give cross-phase visibility (stale L1/XCD-L2 on ping-pong reuse).
// R14 = revert to R12 (419us, known-good) + safe dispatch reduction:
//  (1) build_kernel = count_fill + xw merged (independent; block-range split;
//      count_fill keeps blockIdx&7 XCD partitioning).
//  (2) stats reduce fused into layer_kernel via last-block-done pattern
//      (threadfence + device-scope atomic ticket; last block reduces
//      partials->stats; consumed by the NEXT kernel -> kernel-boundary
//      coherence, no grid barrier needed). 13 kernel dispatches -> 7.

constexpr int N = 50000;
constexpr int E = 800000;
constexpr int G = 128;
constexpr int MAXDEG = 64;
constexpr int NPART = 8;
constexpr int PART_SZ = (N + NPART - 1) / NPART;   // 6250
constexpr int CF_BLOCKS = NPART * ((E + 255) / 256);  // 25000
constexpr int NB_TILES = (N + 63) / 64;            // 782
constexpr float BN_EPS = 1e-5f;

__device__ inline float4 ld4(const float* p) { return *(const float4*)p; }
__device__ inline void st4(float* p, float4 v) { *(float4*)p = v; }

union HF2 { __half2 h2[2]; float2 f2; };

// blocks [0, CF_BLOCKS): count_fill, partition b&7, edge chunk b>>3.
// blocks [CF_BLOCKS, CF_BLOCKS+NB_TILES): xw tile (independent work).
__global__ __launch_bounds__(256) void build_kernel(
    const int* __restrict__ ei, int* __restrict__ deg, unsigned short* __restrict__ ell,
    const float* __restrict__ x, const float* __restrict__ W, __half* __restrict__ out)
{
    int tid = threadIdx.x;
    if (blockIdx.x < CF_BLOCKS) {
        int part = blockIdx.x & (NPART - 1);
        int e = (blockIdx.x >> 3) * 256 + tid;
        if (e < E) {
            int d = ei[E + e];
            if (d / PART_SZ == part) {
                int s = ei[e];
                int slot = atomicAdd(&deg[d], 1);
                if (slot < MAXDEG) ell[(size_t)d * MAXDEG + slot] = (unsigned short)s;
            }
        }
        return;
    }

    int tile = blockIdx.x - CF_BLOCKS;
    int ty = tid >> 4, tx = tid & 15;
    int base = tile * 64;

    float acc[4][4];
#pragma unroll
    for (int r = 0; r < 4; r++)
#pragma unroll
        for (int cc = 0; cc < 4; cc++) acc[r][cc] = 0.f;

    int rr[4];
#pragma unroll
    for (int r = 0; r < 4; r++) rr[r] = min(base + 4 * ty + r, N - 1);

#pragma unroll 4
    for (int c = 0; c < 128; c++) {
        float4 w4 = ld4(W + c * 64 + 4 * tx);
#pragma unroll
        for (int r = 0; r < 4; r++) {
            float a = x[(size_t)rr[r] * 128 + c];
            acc[r][0] += a * w4.x; acc[r][1] += a * w4.y;
            acc[r][2] += a * w4.z; acc[r][3] += a * w4.w;
        }
    }
#pragma unroll
    for (int r = 0; r < 4; r++) {
        int node = base + 4 * ty + r;
        if (node < N) {
            HF2 u;
            u.h2[0] = __floats2half2_rn(acc[r][0], acc[r][1]);
            u.h2[1] = __floats2half2_rn(acc[r][2], acc[r][3]);
            *(float2*)(out + (size_t)node * 64 + 4 * tx) = u.f2;
        }
    }
}

// Fused GIN layer. hin fp16, N+1 rows (row N = zeros). 64 nodes per block.
// ELL has N+1 rows; row N and all slots >= deg are 0xFFFF (clamped to N).
// Epilogue: per-block partials + last-block-done reduction into statsOut.
template <bool FIRST>
__global__ __launch_bounds__(256) void layer_kernel(
    const __half* __restrict__ hin, const unsigned short* __restrict__ ell,
    const int* __restrict__ deg,
    const float* __restrict__ statsPrev, const float* __restrict__ gamma, const float* __restrict__ beta,
    const float* __restrict__ bias0,
    const float* __restrict__ W1, const float* __restrict__ b1,
    const float* __restrict__ W2, const float* __restrict__ b2,
    __half* __restrict__ hout, float* __restrict__ statsPart,
    float* __restrict__ statsOut, int* __restrict__ doneCnt)
{
    __shared__ float sV[64 * 68];   // stride 68
    __shared__ float sStat[128];
    __shared__ int sTicket;

    int tid = threadIdx.x, lane = tid & 63, wv = tid >> 6;
    if (tid < 128) sStat[tid] = 0.f;

    int base = blockIdx.x * 64;
    int n8 = lane >> 3, f = lane & 7;   // node-sub (8), feature-oct (8)

    // per-lane channel oct f*8..f*8+7 epilogue params
    float sc[8], sh[8], b0[8];
    if constexpr (FIRST) {
#pragma unroll
        for (int q = 0; q < 2; q++) {
            float4 b4 = ld4(bias0 + 8 * f + 4 * q);
            b0[4 * q + 0] = b4.x; b0[4 * q + 1] = b4.y;
            b0[4 * q + 2] = b4.z; b0[4 * q + 3] = b4.w;
        }
    } else {
#pragma unroll
        for (int q = 0; q < 2; q++) {
            float4 s1 = ld4(statsPrev + 8 * f + 4 * q);
            float4 s2 = ld4(statsPrev + 64 + 8 * f + 4 * q);
            float4 g4 = ld4(gamma + 8 * f + 4 * q);
            float4 be4 = ld4(beta + 8 * f + 4 * q);
            float m[4] = { s1.x / N, s1.y / N, s1.z / N, s1.w / N };
            float v2[4] = { s2.x / N, s2.y / N, s2.z / N, s2.w / N };
            float gg[4] = { g4.x, g4.y, g4.z, g4.w };
            float bb4[4] = { be4.x, be4.y, be4.z, be4.w };
#pragma unroll
            for (int i = 0; i < 4; i++) {
                float s = gg[i] * rsqrtf(v2[i] - m[i] * m[i] + BN_EPS);
                sc[4 * q + i] = s;
                sh[4 * q + i] = bb4[i] - m[i] * s;
            }
        }
    }

    // ---- phase A: merged 2-deep gather; lane owns nodeA (slots 0-7) and nodeB (8-15) ----
    {
        int nodeA = base + wv * 16 + n8;
        int nodeB = nodeA + 8;
        int ndA = (nodeA < N) ? nodeA : N;
        int ndB = (nodeB < N) ? nodeB : N;
        int dgA = (nodeA < N) ? deg[nodeA] : 0;
        int dgB = (nodeB < N) ? deg[nodeB] : 0;
        int pA = (min(dgA, MAXDEG) + 7) & ~7;
        int pB = (min(dgB, MAXDEG) + 7) & ~7;
        int pm = max(pA, pB);
        const unsigned short* rowA = ell + (size_t)ndA * MAXDEG;
        const unsigned short* rowB = ell + (size_t)ndB * MAXDEG;

        __half2 apA[4][4], apB[4][4];
        __half2 z2 = __half2(__float2half(0.f), __float2half(0.f));
#pragma unroll
        for (int r = 0; r < 4; r++)
#pragma unroll
            for (int k = 0; k < 4; k++) { apA[r][k] = z2; apB[r][k] = z2; }

        float4 rownA = ld4((const float*)(hin + (size_t)ndA * 64 + 8 * f));
        float4 rownB = ld4((const float*)(hin + (size_t)ndB * 64 + 8 * f));

        for (int j = 0; j < pm; j += 8) {
            uint4 ivA = *(const uint4*)(rowA + j);
            uint4 ivB = *(const uint4*)(rowB + j);
            int a0 = min((int)(ivA.x & 0xFFFFu), N), a1 = min((int)(ivA.x >> 16), N);
            int a2 = min((int)(ivA.y & 0xFFFFu), N), a3 = min((int)(ivA.y >> 16), N);
            int a4 = min((int)(ivA.z & 0xFFFFu), N), a5 = min((int)(ivA.z >> 16), N);
            int a6 = min((int)(ivA.w & 0xFFFFu), N), a7 = min((int)(ivA.w >> 16), N);
            int b0i = min((int)(ivB.x & 0xFFFFu), N), b1i = min((int)(ivB.x >> 16), N);
            int b2i = min((int)(ivB.y & 0xFFFFu), N), b3i = min((int)(ivB.y >> 16), N);
            int b4i = min((int)(ivB.z & 0xFFFFu), N), b5i = min((int)(ivB.z >> 16), N);
            int b6i = min((int)(ivB.w & 0xFFFFu), N), b7i = min((int)(ivB.w >> 16), N);
            float4 rA0 = ld4((const float*)(hin + (size_t)a0 * 64 + 8 * f));
            float4 rA1 = ld4((const float*)(hin + (size_t)a1 * 64 + 8 * f));
            float4 rA2 = ld4((const float*)(hin + (size_t)a2 * 64 + 8 * f));
            float4 rA3 = ld4((const float*)(hin + (size_t)a3 * 64 + 8 * f));
            float4 rA4 = ld4((const float*)(hin + (size_t)a4 * 64 + 8 * f));
            float4 rA5 = ld4((const float*)(hin + (size_t)a5 * 64 + 8 * f));
            float4 rA6 = ld4((const float*)(hin + (size_t)a6 * 64 + 8 * f));
            float4 rA7 = ld4((const float*)(hin + (size_t)a7 * 64 + 8 * f));
            float4 rB0 = ld4((const float*)(hin + (size_t)b0i * 64 + 8 * f));
            float4 rB1 = ld4((const float*)(hin + (size_t)b1i * 64 + 8 * f));
            float4 rB2 = ld4((const float*)(hin + (size_t)b2i * 64 + 8 * f));
            float4 rB3 = ld4((const float*)(hin + (size_t)b3i * 64 + 8 * f));
            float4 rB4 = ld4((const float*)(hin + (size_t)b4i * 64 + 8 * f));
            float4 rB5 = ld4((const float*)(hin + (size_t)b5i * 64 + 8 * f));
            float4 rB6 = ld4((const float*)(hin + (size_t)b6i * 64 + 8 * f));
            float4 rB7 = ld4((const float*)(hin + (size_t)b7i * 64 + 8 * f));
            const __half2* hA0 = (const __half2*)&rA0; const __half2* hA1 = (const __half2*)&rA1;
            const __half2* hA2 = (const __half2*)&rA2; const __half2* hA3 = (const __half2*)&rA3;
            const __half2* hA4 = (const __half2*)&rA4; const __half2* hA5 = (const __half2*)&rA5;
            const __half2* hA6 = (const __half2*)&rA6; const __half2* hA7 = (const __half2*)&rA7;
            const __half2* hB0 = (const __half2*)&rB0; const __half2* hB1 = (const __half2*)&rB1;
            const __half2* hB2 = (const __half2*)&rB2; const __half2* hB3 = (const __half2*)&rB3;
            const __half2* hB4 = (const __half2*)&rB4; const __half2* hB5 = (const __half2*)&rB5;
            const __half2* hB6 = (const __half2*)&rB6; const __half2* hB7 = (const __half2*)&rB7;
#pragma unroll
            for (int k = 0; k < 4; k++) {
                apA[0][k] = __hadd2(apA[0][k], __hadd2(hA0[k], hA4[k]));
                apA[1][k] = __hadd2(apA[1][k], __hadd2(hA1[k], hA5[k]));
                apA[2][k] = __hadd2(apA[2][k], __hadd2(hA2[k], hA6[k]));
                apA[3][k] = __hadd2(apA[3][k], __hadd2(hA3[k], hA7[k]));
                apB[0][k] = __hadd2(apB[0][k], __hadd2(hB0[k], hB4[k]));
                apB[1][k] = __hadd2(apB[1][k], __hadd2(hB1[k], hB5[k]));
                apB[2][k] = __hadd2(apB[2][k], __hadd2(hB2[k], hB6[k]));
                apB[3][k] = __hadd2(apB[3][k], __hadd2(hB3[k], hB7[k]));
            }
        }

        // epilogue: fp32 combine of partials + own row, per node
        const __half2* hoA = (const __half2*)&rownA;
        const __half2* hoB = (const __half2*)&rownB;
        float vA[8], vB[8];
#pragma unroll
        for (int k = 0; k < 4; k++) {
            float2 sA = __half22float2(hoA[k]);
            float2 sB = __half22float2(hoB[k]);
#pragma unroll
            for (int r = 0; r < 4; r++) {
                float2 fa = __half22float2(apA[r][k]);
                float2 fb = __half22float2(apB[r][k]);
                sA.x += fa.x; sA.y += fa.y;
                sB.x += fb.x; sB.y += fb.y;
            }
            if constexpr (FIRST) {
                vA[2 * k]     = fmaxf(sA.x + b0[2 * k], 0.f);
                vA[2 * k + 1] = fmaxf(sA.y + b0[2 * k + 1], 0.f);
                vB[2 * k]     = fmaxf(sB.x + b0[2 * k], 0.f);
                vB[2 * k + 1] = fmaxf(sB.y + b0[2 * k + 1], 0.f);
            } else {
                float dshA = (float)(1 + dgA);
                float dshB = (float)(1 + dgB);
                vA[2 * k]     = sc[2 * k] * sA.x + dshA * sh[2 * k];
                vA[2 * k + 1] = sc[2 * k + 1] * sA.y + dshA * sh[2 * k + 1];
                vB[2 * k]     = sc[2 * k] * sB.x + dshB * sh[2 * k];
                vB[2 * k + 1] = sc[2 * k + 1] * sB.y + dshB * sh[2 * k + 1];
            }
        }
        int ridxA = wv * 16 + n8;
        int ridxB = wv * 16 + 8 + n8;
        st4(sV + ridxA * 68 + 8 * f,     make_float4(vA[0], vA[1], vA[2], vA[3]));
        st4(sV + ridxA * 68 + 8 * f + 4, make_float4(vA[4], vA[5], vA[6], vA[7]));
        st4(sV + ridxB * 68 + 8 * f,     make_float4(vB[0], vB[1], vB[2], vB[3]));
        st4(sV + ridxB * 68 + 8 * f + 4, make_float4(vB[4], vB[5], vB[6], vB[7]));
    }
    __syncthreads();

    int ty = tid >> 4, tx = tid & 15;

    if constexpr (!FIRST) {
        // ---- phase B: H = relu(V @ W1 + b1), in-place into sV ----
        float acc[4][4];
#pragma unroll
        for (int cc = 0; cc < 4; cc++) {
            float b = b1[4 * tx + cc];
            acc[0][cc] = b; acc[1][cc] = b; acc[2][cc] = b; acc[3][cc] = b;
        }
#pragma unroll 4
        for (int c = 0; c < 64; c++) {
            float4 w4 = ld4(W1 + c * 64 + 4 * tx);
#pragma unroll
            for (int r = 0; r < 4; r++) {
                float a = sV[(4 * ty + r) * 68 + c];
                acc[r][0] += a * w4.x; acc[r][1] += a * w4.y;
                acc[r][2] += a * w4.z; acc[r][3] += a * w4.w;
            }
        }
        __syncthreads();
#pragma unroll
        for (int r = 0; r < 4; r++)
            st4(sV + (4 * ty + r) * 68 + 4 * tx,
                make_float4(fmaxf(acc[r][0], 0.f), fmaxf(acc[r][1], 0.f),
                            fmaxf(acc[r][2], 0.f), fmaxf(acc[r][3], 0.f)));
        __syncthreads();
    }

    // ---- phase C: O = relu(V @ W2 + b2), store fp16, stats fp32 ----
    float acc[4][4];
#pragma unroll
    for (int cc = 0; cc < 4; cc++) {
        float b = b2[4 * tx + cc];
        acc[0][cc] = b; acc[1][cc] = b; acc[2][cc] = b; acc[3][cc] = b;
    }
#pragma unroll 4
    for (int c = 0; c < 64; c++) {
        float4 w4 = ld4(W2 + c * 64 + 4 * tx);
#pragma unroll
        for (int r = 0; r < 4; r++) {
            float a = sV[(4 * ty + r) * 68 + c];
            acc[r][0] += a * w4.x; acc[r][1] += a * w4.y;
            acc[r][2] += a * w4.z; acc[r][3] += a * w4.w;
        }
    }
#pragma unroll
    for (int r = 0; r < 4; r++) {
        int node = base + 4 * ty + r;
        if (node < N) {
            acc[r][0] = fmaxf(acc[r][0], 0.f); acc[r][1] = fmaxf(acc[r][1], 0.f);
            acc[r][2] = fmaxf(acc[r][2], 0.f); acc[r][3] = fmaxf(acc[r][3], 0.f);
            HF2 u;
            u.h2[0] = __floats2half2_rn(acc[r][0], acc[r][1]);
            u.h2[1] = __floats2half2_rn(acc[r][2], acc[r][3]);
            *(float2*)(hout + (size_t)node * 64 + 4 * tx) = u.f2;
        } else {
            acc[r][0] = acc[r][1] = acc[r][2] = acc[r][3] = 0.f;
        }
    }
#pragma unroll
    for (int cc = 0; cc < 4; cc++) {
        float s = 0.f, q = 0.f;
#pragma unroll
        for (int r = 0; r < 4; r++) { s += acc[r][cc]; q += acc[r][cc] * acc[r][cc]; }
        atomicAdd(&sStat[4 * tx + cc], s);
        atomicAdd(&sStat[64 + 4 * tx + cc], q);
    }
    __syncthreads();
    if (tid < 128) statsPart[(size_t)blockIdx.x * 128 + tid] = sStat[tid];

    // ---- fused cross-block stats reduction: last block to finish does it ----
    __threadfence();                      // release partials (device scope)
    if (tid == 0) sTicket = atomicAdd(doneCnt, 1);
    __syncthreads();
    if (sTicket == (int)gridDim.x - 1) {
        __threadfence();                  // acquire others' partials
        if (tid < 128) {
            float s = 0.f;
            for (int i = 0; i < (int)gridDim.x; i++)
                s += statsPart[(size_t)i * 128 + tid];   // coalesced across tid
            statsOut[tid] = s;
        }
    }
}

// pooled[g] = scale*sum_{n in g} h[n] + cnt*shift; z=relu(p@fc1+b1); z@fc2+b2; log_softmax
// Vectorized: 8 lanes x float4 (16B) cover one 128B row; 32 rows/iteration.
__global__ __launch_bounds__(256) void pool_head_kernel(
    const __half* __restrict__ h, const int* __restrict__ batch,
    const float* __restrict__ stats, const float* __restrict__ gamma, const float* __restrict__ beta,
    const float* __restrict__ fc1w, const float* __restrict__ fc1b,
    const float* __restrict__ fc2w, const float* __restrict__ fc2b,
    float* __restrict__ out)
{
    __shared__ float red[32][65];
    __shared__ float sp[64];
    __shared__ float sz[64];
    __shared__ float so[10];

    int tid = threadIdx.x;
    int g = blockIdx.x;

    int start, end;
    {
        int lo = 0, hi = N;
        while (lo < hi) { int mid = (lo + hi) >> 1; if (batch[mid] < g) lo = mid + 1; else hi = mid; }
        start = lo;
        lo = start; hi = N;
        while (lo < hi) { int mid = (lo + hi) >> 1; if (batch[mid] < g + 1) lo = mid + 1; else hi = mid; }
        end = lo;
    }

    int q = tid >> 3, sub = tid & 7;
    float a[8];
#pragma unroll
    for (int k = 0; k < 8; k++) a[k] = 0.f;

    for (int node = start + q; node < end; node += 32) {
        float4 raw = ld4((const float*)(h + (size_t)node * 64 + 8 * sub));
        const __half2* hh = (const __half2*)&raw;
#pragma unroll
        for (int k = 0; k < 4; k++) {
            float2 f2 = __half22float2(hh[k]);
            a[2 * k] += f2.x; a[2 * k + 1] += f2.y;
        }
    }
#pragma unroll
    for (int k = 0; k < 8; k++) red[q][8 * sub + k] = a[k];
    __syncthreads();

    if (tid < 64) {
        float t = 0.f;
#pragma unroll
        for (int qq = 0; qq < 32; qq++) t += red[qq][tid];
        float mean = stats[tid] * (1.f / N);
        float var  = stats[64 + tid] * (1.f / N) - mean * mean;
        float sc = gamma[tid] * rsqrtf(var + BN_EPS);
        float sh = beta[tid] - mean * sc;
        sp[tid] = sc * t + (float)(end - start) * sh;
    }
    __syncthreads();
    if (tid < 64) {
        float a1 = fc1b[tid];
#pragma unroll
        for (int c = 0; c < 64; c++) a1 += sp[c] * fc1w[c * 64 + tid];
        sz[tid] = fmaxf(a1, 0.f);
    }
    __syncthreads();
    if (tid < 10) {
        float z = fc2b[tid];
#pragma unroll
        for (int j = 0; j < 64; j++) z += sz[j] * fc2w[j * 10 + tid];
        so[tid] = z;
    }
    __syncthreads();
    if (tid < 10) {
        float m = -1e30f;
#pragma unroll
        for (int c = 0; c < 10; c++) m = fmaxf(m, so[c]);
        float s = 0.f;
#pragma unroll
        for (int c = 0; c < 10; c++) s += expf(so[c] - m);
        out[g * 10 + tid] = so[tid] - m - logf(s);
    }
}

extern "C" void kernel_launch(void* const* d_in, const int* in_sizes, int n_in,
                              void* d_out, int out_size, void* d_ws, size_t ws_size,
                              hipStream_t stream)
{
    const float* x    = (const float*)d_in[0];
    const int*   ei   = (const int*)  d_in[1];
    const int*   batch= (const int*)  d_in[2];
    const float* W1a  = (const float*)d_in[3];
    const float* b1a  = (const float*)d_in[4];
    const float* W1b  = (const float*)d_in[5];
    const float* b1b  = (const float*)d_in[6];
    const float* Wa   = (const float*)d_in[7];
    const float* ba   = (const float*)d_in[8];
    const float* Wb   = (const float*)d_in[9];
    const float* bb   = (const float*)d_in[10];
    const float* gammas = (const float*)d_in[11];
    const float* betas  = (const float*)d_in[12];
    const float* fc1w = (const float*)d_in[13];
    const float* fc1b = (const float*)d_in[14];
    const float* fc2w = (const float*)d_in[15];
    const float* fc2b = (const float*)d_in[16];
    float* out = (float*)d_out;

    // workspace carve (ell has N+1 rows; row N = all-0xFFFF sentinel)
    char* w = (char*)d_ws;
    int*            deg      = (int*)w;                      // @0          200,000 B (zeroed)
    int*            doneCnt  = (int*)(w + 200000);           // @200,000    5*4 B (zeroed)
    float*          stats    = (float*)(w + 200704);         // @200,704    2,560 B
    unsigned short* ell      = (unsigned short*)(w + 203264);// @203,264    6,400,128 B (0xFF)
    __half*         bufA     = (__half*)(w + 6603392);       // @6,603,392  6,400,128 B
    __half*         bufB     = (__half*)(w + 13003520);      // @13,003,520 6,400,128 B
    float*          partials = (float*)(w + 19403648);       // @19,403,648 400,384 B

    hipMemsetAsync(deg, 0, 200020, stream);                  // deg + 5 counters
    hipMemsetAsync(ell, 0xFF, 6400128, stream);
    hipMemsetAsync(bufA + (size_t)N * 64, 0, 128, stream);   // zero row N
    hipMemsetAsync(bufB + (size_t)N * 64, 0, 128, stream);

    build_kernel<<<CF_BLOCKS + NB_TILES, 256, 0, stream>>>(ei, deg, ell, x, W1a, bufA);

    layer_kernel<true><<<NB_TILES, 256, 0, stream>>>(
        bufA, ell, deg, nullptr, nullptr, nullptr, b1a,
        nullptr, nullptr, W1b, b1b, bufB, partials, stats, doneCnt);

    layer_kernel<false><<<NB_TILES, 256, 0, stream>>>(
        bufB, ell, deg, stats, gammas, betas, nullptr,
        Wa, ba, Wb, bb, bufA, partials, stats + 128, doneCnt + 1);

    layer_kernel<false><<<NB_TILES, 256, 0, stream>>>(
        bufA, ell, deg, stats + 128, gammas + 64, betas + 64, nullptr,
        Wa + 4096, ba + 64, Wb + 4096, bb + 64, bufB, partials, stats + 256, doneCnt + 2);

    layer_kernel<false><<<NB_TILES, 256, 0, stream>>>(
        bufB, ell, deg, stats + 256, gammas + 128, betas + 128, nullptr,
        Wa + 8192, ba + 128, Wb + 8192, bb + 128, bufA, partials, stats + 384, doneCnt + 3);

    layer_kernel<false><<<NB_TILES, 256, 0, stream>>>(
        bufA, ell, deg, stats + 384, gammas + 192, betas + 192, nullptr,
        Wa + 12288, ba + 192, Wb + 12288, bb + 192, bufB, partials, stats + 512, doneCnt + 4);

    pool_head_kernel<<<G, 256, 0, stream>>>(
        bufB, batch, stats + 512, gammas + 256, betas + 256,
        fc1w, fc1b, fc2w, fc2b, out);
}

// Round 13
// 428.454 us; speedup vs baseline: 3.6677x; 3.6677x over previous
//
#include <hip/hip_runtime.h>
#include <hip/hip_fp16.h>

// GIN (5 layers) + BN + pool + MLP head, fused pipeline for MI355X. Round 15.
// R13 (grid.sync mega-kernel): WRONG RESULTS. R14 (last-block-done + fence):
// 3.7x SLOWER (per-block device fences poisoned every layer; one dispatch hit
// 30ms). Lesson: kernel-boundary coherence is cheap here; in-kernel
// cross-block signaling is not. R15 = R12 (419us known-good) + the one safe
// fusion: build_kernel = count_fill + xw by block-range split (independent
// work, no signaling; both outputs consumed by the NEXT kernel). count_fill
// keeps blockIdx&7 XCD partitioning (CF_BLOCKS % 8 == 0). reduce_stats stays
// a separate tiny kernel (proven pattern).

constexpr int N = 50000;
constexpr int E = 800000;
constexpr int G = 128;
constexpr int MAXDEG = 64;
constexpr int NPART = 8;
constexpr int PART_SZ = (N + NPART - 1) / NPART;      // 6250
constexpr int CF_BLOCKS = NPART * ((E + 255) / 256);  // 25000 (mult of 8)
constexpr int NB_TILES = (N + 63) / 64;               // 782
constexpr float BN_EPS = 1e-5f;

__device__ inline float4 ld4(const float* p) { return *(const float4*)p; }
__device__ inline void st4(float* p, float4 v) { *(float4*)p = v; }

union HF2 { __half2 h2[2]; float2 f2; };

// blocks [0, CF_BLOCKS): count_fill, partition b&7, edge chunk b>>3.
// blocks [CF_BLOCKS, CF_BLOCKS+NB_TILES): xw tile (independent work).
__global__ __launch_bounds__(256) void build_kernel(
    const int* __restrict__ ei, int* __restrict__ deg, unsigned short* __restrict__ ell,
    const float* __restrict__ x, const float* __restrict__ W, __half* __restrict__ out)
{
    int tid = threadIdx.x;
    if (blockIdx.x < CF_BLOCKS) {
        int part = blockIdx.x & (NPART - 1);
        int e = (blockIdx.x >> 3) * 256 + tid;
        if (e < E) {
            int d = ei[E + e];
            if (d / PART_SZ == part) {
                int s = ei[e];
                int slot = atomicAdd(&deg[d], 1);
                if (slot < MAXDEG) ell[(size_t)d * MAXDEG + slot] = (unsigned short)s;
            }
        }
        return;
    }

    int tile = blockIdx.x - CF_BLOCKS;
    int ty = tid >> 4, tx = tid & 15;
    int base = tile * 64;

    float acc[4][4];
#pragma unroll
    for (int r = 0; r < 4; r++)
#pragma unroll
        for (int cc = 0; cc < 4; cc++) acc[r][cc] = 0.f;

    int rr[4];
#pragma unroll
    for (int r = 0; r < 4; r++) rr[r] = min(base + 4 * ty + r, N - 1);

#pragma unroll 4
    for (int c = 0; c < 128; c++) {
        float4 w4 = ld4(W + c * 64 + 4 * tx);
#pragma unroll
        for (int r = 0; r < 4; r++) {
            float a = x[(size_t)rr[r] * 128 + c];
            acc[r][0] += a * w4.x; acc[r][1] += a * w4.y;
            acc[r][2] += a * w4.z; acc[r][3] += a * w4.w;
        }
    }
#pragma unroll
    for (int r = 0; r < 4; r++) {
        int node = base + 4 * ty + r;
        if (node < N) {
            HF2 u;
            u.h2[0] = __floats2half2_rn(acc[r][0], acc[r][1]);
            u.h2[1] = __floats2half2_rn(acc[r][2], acc[r][3]);
            *(float2*)(out + (size_t)node * 64 + 4 * tx) = u.f2;
        }
    }
}

// sum nb per-block partials (each 128 floats) into stats[128].
__global__ __launch_bounds__(64) void reduce_stats_kernel(
    const float* __restrict__ partials, float* __restrict__ stats, int nb)
{
    int c = blockIdx.x;
    int lane = threadIdx.x;
    float s = 0.f;
    for (int i = lane; i < nb; i += 64)
        s += partials[(size_t)i * 128 + c];
#pragma unroll
    for (int off = 32; off > 0; off >>= 1)
        s += __shfl_down(s, off, 64);
    if (lane == 0) stats[c] = s;
}

// Fused GIN layer. hin fp16, N+1 rows (row N = zeros). 64 nodes per block.
// ELL has N+1 rows; row N and all slots >= deg are 0xFFFF (clamped to N).
template <bool FIRST>
__global__ __launch_bounds__(256) void layer_kernel(
    const __half* __restrict__ hin, const unsigned short* __restrict__ ell,
    const int* __restrict__ deg,
    const float* __restrict__ statsPrev, const float* __restrict__ gamma, const float* __restrict__ beta,
    const float* __restrict__ bias0,
    const float* __restrict__ W1, const float* __restrict__ b1,
    const float* __restrict__ W2, const float* __restrict__ b2,
    __half* __restrict__ hout, float* __restrict__ statsPart)
{
    __shared__ float sV[64 * 68];   // stride 68
    __shared__ float sStat[128];

    int tid = threadIdx.x, lane = tid & 63, wv = tid >> 6;
    if (tid < 128) sStat[tid] = 0.f;

    int base = blockIdx.x * 64;
    int n8 = lane >> 3, f = lane & 7;   // node-sub (8), feature-oct (8)

    // per-lane channel oct f*8..f*8+7 epilogue params
    float sc[8], sh[8], b0[8];
    if constexpr (FIRST) {
#pragma unroll
        for (int q = 0; q < 2; q++) {
            float4 b4 = ld4(bias0 + 8 * f + 4 * q);
            b0[4 * q + 0] = b4.x; b0[4 * q + 1] = b4.y;
            b0[4 * q + 2] = b4.z; b0[4 * q + 3] = b4.w;
        }
    } else {
#pragma unroll
        for (int q = 0; q < 2; q++) {
            float4 s1 = ld4(statsPrev + 8 * f + 4 * q);
            float4 s2 = ld4(statsPrev + 64 + 8 * f + 4 * q);
            float4 g4 = ld4(gamma + 8 * f + 4 * q);
            float4 be4 = ld4(beta + 8 * f + 4 * q);
            float m[4] = { s1.x / N, s1.y / N, s1.z / N, s1.w / N };
            float v2[4] = { s2.x / N, s2.y / N, s2.z / N, s2.w / N };
            float gg[4] = { g4.x, g4.y, g4.z, g4.w };
            float bb4[4] = { be4.x, be4.y, be4.z, be4.w };
#pragma unroll
            for (int i = 0; i < 4; i++) {
                float s = gg[i] * rsqrtf(v2[i] - m[i] * m[i] + BN_EPS);
                sc[4 * q + i] = s;
                sh[4 * q + i] = bb4[i] - m[i] * s;
            }
        }
    }

    // ---- phase A: merged 2-deep gather; lane owns nodeA (slots 0-7) and nodeB (8-15) ----
    {
        int nodeA = base + wv * 16 + n8;
        int nodeB = nodeA + 8;
        int ndA = (nodeA < N) ? nodeA : N;
        int ndB = (nodeB < N) ? nodeB : N;
        int dgA = (nodeA < N) ? deg[nodeA] : 0;
        int dgB = (nodeB < N) ? deg[nodeB] : 0;
        int pA = (min(dgA, MAXDEG) + 7) & ~7;
        int pB = (min(dgB, MAXDEG) + 7) & ~7;
        int pm = max(pA, pB);
        const unsigned short* rowA = ell + (size_t)ndA * MAXDEG;
        const unsigned short* rowB = ell + (size_t)ndB * MAXDEG;

        __half2 apA[4][4], apB[4][4];
        __half2 z2 = __half2(__float2half(0.f), __float2half(0.f));
#pragma unroll
        for (int r = 0; r < 4; r++)
#pragma unroll
            for (int k = 0; k < 4; k++) { apA[r][k] = z2; apB[r][k] = z2; }

        float4 rownA = ld4((const float*)(hin + (size_t)ndA * 64 + 8 * f));
        float4 rownB = ld4((const float*)(hin + (size_t)ndB * 64 + 8 * f));

        for (int j = 0; j < pm; j += 8) {
            uint4 ivA = *(const uint4*)(rowA + j);
            uint4 ivB = *(const uint4*)(rowB + j);
            int a0 = min((int)(ivA.x & 0xFFFFu), N), a1 = min((int)(ivA.x >> 16), N);
            int a2 = min((int)(ivA.y & 0xFFFFu), N), a3 = min((int)(ivA.y >> 16), N);
            int a4 = min((int)(ivA.z & 0xFFFFu), N), a5 = min((int)(ivA.z >> 16), N);
            int a6 = min((int)(ivA.w & 0xFFFFu), N), a7 = min((int)(ivA.w >> 16), N);
            int b0i = min((int)(ivB.x & 0xFFFFu), N), b1i = min((int)(ivB.x >> 16), N);
            int b2i = min((int)(ivB.y & 0xFFFFu), N), b3i = min((int)(ivB.y >> 16), N);
            int b4i = min((int)(ivB.z & 0xFFFFu), N), b5i = min((int)(ivB.z >> 16), N);
            int b6i = min((int)(ivB.w & 0xFFFFu), N), b7i = min((int)(ivB.w >> 16), N);
            float4 rA0 = ld4((const float*)(hin + (size_t)a0 * 64 + 8 * f));
            float4 rA1 = ld4((const float*)(hin + (size_t)a1 * 64 + 8 * f));
            float4 rA2 = ld4((const float*)(hin + (size_t)a2 * 64 + 8 * f));
            float4 rA3 = ld4((const float*)(hin + (size_t)a3 * 64 + 8 * f));
            float4 rA4 = ld4((const float*)(hin + (size_t)a4 * 64 + 8 * f));
            float4 rA5 = ld4((const float*)(hin + (size_t)a5 * 64 + 8 * f));
            float4 rA6 = ld4((const float*)(hin + (size_t)a6 * 64 + 8 * f));
            float4 rA7 = ld4((const float*)(hin + (size_t)a7 * 64 + 8 * f));
            float4 rB0 = ld4((const float*)(hin + (size_t)b0i * 64 + 8 * f));
            float4 rB1 = ld4((const float*)(hin + (size_t)b1i * 64 + 8 * f));
            float4 rB2 = ld4((const float*)(hin + (size_t)b2i * 64 + 8 * f));
            float4 rB3 = ld4((const float*)(hin + (size_t)b3i * 64 + 8 * f));
            float4 rB4 = ld4((const float*)(hin + (size_t)b4i * 64 + 8 * f));
            float4 rB5 = ld4((const float*)(hin + (size_t)b5i * 64 + 8 * f));
            float4 rB6 = ld4((const float*)(hin + (size_t)b6i * 64 + 8 * f));
            float4 rB7 = ld4((const float*)(hin + (size_t)b7i * 64 + 8 * f));
            const __half2* hA0 = (const __half2*)&rA0; const __half2* hA1 = (const __half2*)&rA1;
            const __half2* hA2 = (const __half2*)&rA2; const __half2* hA3 = (const __half2*)&rA3;
            const __half2* hA4 = (const __half2*)&rA4; const __half2* hA5 = (const __half2*)&rA5;
            const __half2* hA6 = (const __half2*)&rA6; const __half2* hA7 = (const __half2*)&rA7;
            const __half2* hB0 = (const __half2*)&rB0; const __half2* hB1 = (const __half2*)&rB1;
            const __half2* hB2 = (const __half2*)&rB2; const __half2* hB3 = (const __half2*)&rB3;
            const __half2* hB4 = (const __half2*)&rB4; const __half2* hB5 = (const __half2*)&rB5;
            const __half2* hB6 = (const __half2*)&rB6; const __half2* hB7 = (const __half2*)&rB7;
#pragma unroll
            for (int k = 0; k < 4; k++) {
                apA[0][k] = __hadd2(apA[0][k], __hadd2(hA0[k], hA4[k]));
                apA[1][k] = __hadd2(apA[1][k], __hadd2(hA1[k], hA5[k]));
                apA[2][k] = __hadd2(apA[2][k], __hadd2(hA2[k], hA6[k]));
                apA[3][k] = __hadd2(apA[3][k], __hadd2(hA3[k], hA7[k]));
                apB[0][k] = __hadd2(apB[0][k], __hadd2(hB0[k], hB4[k]));
                apB[1][k] = __hadd2(apB[1][k], __hadd2(hB1[k], hB5[k]));
                apB[2][k] = __hadd2(apB[2][k], __hadd2(hB2[k], hB6[k]));
                apB[3][k] = __hadd2(apB[3][k], __hadd2(hB3[k], hB7[k]));
            }
        }

        // epilogue: fp32 combine of partials + own row, per node
        const __half2* hoA = (const __half2*)&rownA;
        const __half2* hoB = (const __half2*)&rownB;
        float vA[8], vB[8];
#pragma unroll
        for (int k = 0; k < 4; k++) {
            float2 sA = __half22float2(hoA[k]);
            float2 sB = __half22float2(hoB[k]);
#pragma unroll
            for (int r = 0; r < 4; r++) {
                float2 fa = __half22float2(apA[r][k]);
                float2 fb = __half22float2(apB[r][k]);
                sA.x += fa.x; sA.y += fa.y;
                sB.x += fb.x; sB.y += fb.y;
            }
            if constexpr (FIRST) {
                vA[2 * k]     = fmaxf(sA.x + b0[2 * k], 0.f);
                vA[2 * k + 1] = fmaxf(sA.y + b0[2 * k + 1], 0.f);
                vB[2 * k]     = fmaxf(sB.x + b0[2 * k], 0.f);
                vB[2 * k + 1] = fmaxf(sB.y + b0[2 * k + 1], 0.f);
            } else {
                float dshA = (float)(1 + dgA);
                float dshB = (float)(1 + dgB);
                vA[2 * k]     = sc[2 * k] * sA.x + dshA * sh[2 * k];
                vA[2 * k + 1] = sc[2 * k + 1] * sA.y + dshA * sh[2 * k + 1];
                vB[2 * k]     = sc[2 * k] * sB.x + dshB * sh[2 * k];
                vB[2 * k + 1] = sc[2 * k + 1] * sB.y + dshB * sh[2 * k + 1];
            }
        }
        int ridxA = wv * 16 + n8;
        int ridxB = wv * 16 + 8 + n8;
        st4(sV + ridxA * 68 + 8 * f,     make_float4(vA[0], vA[1], vA[2], vA[3]));
        st4(sV + ridxA * 68 + 8 * f + 4, make_float4(vA[4], vA[5], vA[6], vA[7]));
        st4(sV + ridxB * 68 + 8 * f,     make_float4(vB[0], vB[1], vB[2], vB[3]));
        st4(sV + ridxB * 68 + 8 * f + 4, make_float4(vB[4], vB[5], vB[6], vB[7]));
    }
    __syncthreads();

    int ty = tid >> 4, tx = tid & 15;

    if constexpr (!FIRST) {
        // ---- phase B: H = relu(V @ W1 + b1), in-place into sV ----
        float acc[4][4];
#pragma unroll
        for (int cc = 0; cc < 4; cc++) {
            float b = b1[4 * tx + cc];
            acc[0][cc] = b; acc[1][cc] = b; acc[2][cc] = b; acc[3][cc] = b;
        }
#pragma unroll 4
        for (int c = 0; c < 64; c++) {
            float4 w4 = ld4(W1 + c * 64 + 4 * tx);
#pragma unroll
            for (int r = 0; r < 4; r++) {
                float a = sV[(4 * ty + r) * 68 + c];
                acc[r][0] += a * w4.x; acc[r][1] += a * w4.y;
                acc[r][2] += a * w4.z; acc[r][3] += a * w4.w;
            }
        }
        __syncthreads();
#pragma unroll
        for (int r = 0; r < 4; r++)
            st4(sV + (4 * ty + r) * 68 + 4 * tx,
                make_float4(fmaxf(acc[r][0], 0.f), fmaxf(acc[r][1], 0.f),
                            fmaxf(acc[r][2], 0.f), fmaxf(acc[r][3], 0.f)));
        __syncthreads();
    }

    // ---- phase C: O = relu(V @ W2 + b2), store fp16, stats fp32 ----
    float acc[4][4];
#pragma unroll
    for (int cc = 0; cc < 4; cc++) {
        float b = b2[4 * tx + cc];
        acc[0][cc] = b; acc[1][cc] = b; acc[2][cc] = b; acc[3][cc] = b;
    }
#pragma unroll 4
    for (int c = 0; c < 64; c++) {
        float4 w4 = ld4(W2 + c * 64 + 4 * tx);
#pragma unroll
        for (int r = 0; r < 4; r++) {
            float a = sV[(4 * ty + r) * 68 + c];
            acc[r][0] += a * w4.x; acc[r][1] += a * w4.y;
            acc[r][2] += a * w4.z; acc[r][3] += a * w4.w;
        }
    }
#pragma unroll
    for (int r = 0; r < 4; r++) {
        int node = base + 4 * ty + r;
        if (node < N) {
            acc[r][0] = fmaxf(acc[r][0], 0.f); acc[r][1] = fmaxf(acc[r][1], 0.f);
            acc[r][2] = fmaxf(acc[r][2], 0.f); acc[r][3] = fmaxf(acc[r][3], 0.f);
            HF2 u;
            u.h2[0] = __floats2half2_rn(acc[r][0], acc[r][1]);
            u.h2[1] = __floats2half2_rn(acc[r][2], acc[r][3]);
            *(float2*)(hout + (size_t)node * 64 + 4 * tx) = u.f2;
        } else {
            acc[r][0] = acc[r][1] = acc[r][2] = acc[r][3] = 0.f;
        }
    }
#pragma unroll
    for (int cc = 0; cc < 4; cc++) {
        float s = 0.f, q = 0.f;
#pragma unroll
        for (int r = 0; r < 4; r++) { s += acc[r][cc]; q += acc[r][cc] * acc[r][cc]; }
        atomicAdd(&sStat[4 * tx + cc], s);
        atomicAdd(&sStat[64 + 4 * tx + cc], q);
    }
    __syncthreads();
    if (tid < 128) statsPart[(size_t)blockIdx.x * 128 + tid] = sStat[tid];
}

// pooled[g] = scale*sum_{n in g} h[n] + cnt*shift; z=relu(p@fc1+b1); z@fc2+b2; log_softmax
// Vectorized: 8 lanes x float4 (16B) cover one 128B row; 32 rows/iteration.
__global__ __launch_bounds__(256) void pool_head_kernel(
    const __half* __restrict__ h, const int* __restrict__ batch,
    const float* __restrict__ stats, const float* __restrict__ gamma, const float* __restrict__ beta,
    const float* __restrict__ fc1w, const float* __restrict__ fc1b,
    const float* __restrict__ fc2w, const float* __restrict__ fc2b,
    float* __restrict__ out)
{
    __shared__ float red[32][65];
    __shared__ float sp[64];
    __shared__ float sz[64];
    __shared__ float so[10];

    int tid = threadIdx.x;
    int g = blockIdx.x;

    int start, end;
    {
        int lo = 0, hi = N;
        while (lo < hi) { int mid = (lo + hi) >> 1; if (batch[mid] < g) lo = mid + 1; else hi = mid; }
        start = lo;
        lo = start; hi = N;
        while (lo < hi) { int mid = (lo + hi) >> 1; if (batch[mid] < g + 1) lo = mid + 1; else hi = mid; }
        end = lo;
    }

    int q = tid >> 3, sub = tid & 7;
    float a[8];
#pragma unroll
    for (int k = 0; k < 8; k++) a[k] = 0.f;

    for (int node = start + q; node < end; node += 32) {
        float4 raw = ld4((const float*)(h + (size_t)node * 64 + 8 * sub));
        const __half2* hh = (const __half2*)&raw;
#pragma unroll
        for (int k = 0; k < 4; k++) {
            float2 f2 = __half22float2(hh[k]);
            a[2 * k] += f2.x; a[2 * k + 1] += f2.y;
        }
    }
#pragma unroll
    for (int k = 0; k < 8; k++) red[q][8 * sub + k] = a[k];
    __syncthreads();

    if (tid < 64) {
        float t = 0.f;
#pragma unroll
        for (int qq = 0; qq < 32; qq++) t += red[qq][tid];
        float mean = stats[tid] * (1.f / N);
        float var  = stats[64 + tid] * (1.f / N) - mean * mean;
        float sc = gamma[tid] * rsqrtf(var + BN_EPS);
        float sh = beta[tid] - mean * sc;
        sp[tid] = sc * t + (float)(end - start) * sh;
    }
    __syncthreads();
    if (tid < 64) {
        float a1 = fc1b[tid];
#pragma unroll
        for (int c = 0; c < 64; c++) a1 += sp[c] * fc1w[c * 64 + tid];
        sz[tid] = fmaxf(a1, 0.f);
    }
    __syncthreads();
    if (tid < 10) {
        float z = fc2b[tid];
#pragma unroll
        for (int j = 0; j < 64; j++) z += sz[j] * fc2w[j * 10 + tid];
        so[tid] = z;
    }
    __syncthreads();
    if (tid < 10) {
        float m = -1e30f;
#pragma unroll
        for (int c = 0; c < 10; c++) m = fmaxf(m, so[c]);
        float s = 0.f;
#pragma unroll
        for (int c = 0; c < 10; c++) s += expf(so[c] - m);
        out[g * 10 + tid] = so[tid] - m - logf(s);
    }
}

extern "C" void kernel_launch(void* const* d_in, const int* in_sizes, int n_in,
                              void* d_out, int out_size, void* d_ws, size_t ws_size,
                              hipStream_t stream)
{
    const float* x    = (const float*)d_in[0];
    const int*   ei   = (const int*)  d_in[1];
    const int*   batch= (const int*)  d_in[2];
    const float* W1a  = (const float*)d_in[3];
    const float* b1a  = (const float*)d_in[4];
    const float* W1b  = (const float*)d_in[5];
    const float* b1b  = (const float*)d_in[6];
    const float* Wa   = (const float*)d_in[7];
    const float* ba   = (const float*)d_in[8];
    const float* Wb   = (const float*)d_in[9];
    const float* bb   = (const float*)d_in[10];
    const float* gammas = (const float*)d_in[11];
    const float* betas  = (const float*)d_in[12];
    const float* fc1w = (const float*)d_in[13];
    const float* fc1b = (const float*)d_in[14];
    const float* fc2w = (const float*)d_in[15];
    const float* fc2b = (const float*)d_in[16];
    float* out = (float*)d_out;

    // workspace carve (ell has N+1 rows; row N = all-0xFFFF sentinel)
    char* w = (char*)d_ws;
    int*            deg      = (int*)w;                      // @0          200,000 B (zeroed)
    float*          stats    = (float*)(w + 200704);         // @200,704    2,560 B
    unsigned short* ell      = (unsigned short*)(w + 203264);// @203,264    6,400,128 B (0xFF)
    __half*         bufA     = (__half*)(w + 6603392);       // @6,603,392  6,400,128 B
    __half*         bufB     = (__half*)(w + 13003520);      // @13,003,520 6,400,128 B
    float*          partials = (float*)(w + 19403648);       // @19,403,648 400,384 B

    hipMemsetAsync(deg, 0, 200000, stream);
    hipMemsetAsync(ell, 0xFF, 6400128, stream);
    hipMemsetAsync(bufA + (size_t)N * 64, 0, 128, stream);   // zero row N
    hipMemsetAsync(bufB + (size_t)N * 64, 0, 128, stream);

    build_kernel<<<CF_BLOCKS + NB_TILES, 256, 0, stream>>>(ei, deg, ell, x, W1a, bufA);

    layer_kernel<true><<<NB_TILES, 256, 0, stream>>>(
        bufA, ell, deg, nullptr, nullptr, nullptr, b1a,
        nullptr, nullptr, W1b, b1b, bufB, partials);
    reduce_stats_kernel<<<128, 64, 0, stream>>>(partials, stats, NB_TILES);

    layer_kernel<false><<<NB_TILES, 256, 0, stream>>>(
        bufB, ell, deg, stats, gammas, betas, nullptr,
        Wa, ba, Wb, bb, bufA, partials);
    reduce_stats_kernel<<<128, 64, 0, stream>>>(partials, stats + 128, NB_TILES);

    layer_kernel<false><<<NB_TILES, 256, 0, stream>>>(
        bufA, ell, deg, stats + 128, gammas + 64, betas + 64, nullptr,
        Wa + 4096, ba + 64, Wb + 4096, bb + 64, bufB, partials);
    reduce_stats_kernel<<<128, 64, 0, stream>>>(partials, stats + 256, NB_TILES);

    layer_kernel<false><<<NB_TILES, 256, 0, stream>>>(
        bufB, ell, deg, stats + 256, gammas + 128, betas + 128, nullptr,
        Wa + 8192, ba + 128, Wb + 8192, bb + 128, bufA, partials);
    reduce_stats_kernel<<<128, 64, 0, stream>>>(partials, stats + 384, NB_TILES);

    layer_kernel<false><<<NB_TILES, 256, 0, stream>>>(
        bufA, ell, deg, stats + 384, gammas + 192, betas + 192, nullptr,
        Wa + 12288, ba + 192, Wb + 12288, bb + 192, bufB, partials);
    reduce_stats_kernel<<<128, 64, 0, stream>>>(partials, stats + 512, NB_TILES);

    pool_head_kernel<<<G, 256, 0, stream>>>(
        bufB, batch, stats + 512, gammas + 256, betas + 256,
        fc1w, fc1b, fc2w, fc2b, out);
}

// Round 14
// 417.212 us; speedup vs baseline: 3.7666x; 1.0269x over previous
//
#include <hip/hip_runtime.h>
#include <hip/hip_fp16.h>

// GIN (5 layers) + BN + pool + MLP head, fused pipeline for MI355X. Round 16.
// = R12 verbatim (measured 419us, session best). All three fusion attempts
// regressed for distinct reasons: R13 grid.sync -> stale-cache wrong results;
// R14 per-block device fences -> 3.7x slower; R15 count_fill+xw merge ->
// x-streaming evicted the XCD-partitioned ELL L2 slices (build 97us > parts).
// Layer kernel ~46.5us is invariant across 10 gather variants: the random
// 128B-line stream (~850K lines/layer @ ~2.3TB/s effective) is the floor.
// Structure: ushort ELL (0xFF sentinel + clamp), XCD-partitioned count_fill,
// fp16 feature rows (1 line/row), packed-fp16 gather accum, atomic-free
// stats + tiny reduce kernels, vectorized pool_head.

constexpr int N = 50000;
constexpr int E = 800000;
constexpr int G = 128;
constexpr int MAXDEG = 64;
constexpr int NPART = 8;
constexpr int PART_SZ = (N + NPART - 1) / NPART;   // 6250
constexpr float BN_EPS = 1e-5f;

__device__ inline float4 ld4(const float* p) { return *(const float4*)p; }
__device__ inline void st4(float* p, float4 v) { *(float4*)p = v; }

union HF2 { __half2 h2[2]; float2 f2; };

// block b: partition b&7 (dest range), edge chunk b>>3. One owner per edge.
__global__ __launch_bounds__(256) void count_fill_kernel(
    const int* __restrict__ ei, int* __restrict__ deg, unsigned short* __restrict__ ell)
{
    int part = blockIdx.x & (NPART - 1);
    int e = (blockIdx.x >> 3) * 256 + threadIdx.x;
    if (e < E) {
        int d = ei[E + e];
        if (d / PART_SZ == part) {
            int s = ei[e];
            int slot = atomicAdd(&deg[d], 1);
            if (slot < MAXDEG) ell[(size_t)d * MAXDEG + slot] = (unsigned short)s;
        }
    }
}

// out[n][64] = x[n][128] @ W[128][64], stored fp16; 64 rows per block
__global__ __launch_bounds__(256) void xw_kernel(
    const float* __restrict__ x, const float* __restrict__ W, __half* __restrict__ out)
{
    int tid = threadIdx.x;
    int ty = tid >> 4, tx = tid & 15;
    int base = blockIdx.x * 64;

    float acc[4][4];
#pragma unroll
    for (int r = 0; r < 4; r++)
#pragma unroll
        for (int cc = 0; cc < 4; cc++) acc[r][cc] = 0.f;

    int rr[4];
#pragma unroll
    for (int r = 0; r < 4; r++) rr[r] = min(base + 4 * ty + r, N - 1);

#pragma unroll 4
    for (int c = 0; c < 128; c++) {
        float4 w4 = ld4(W + c * 64 + 4 * tx);
#pragma unroll
        for (int r = 0; r < 4; r++) {
            float a = x[(size_t)rr[r] * 128 + c];
            acc[r][0] += a * w4.x; acc[r][1] += a * w4.y;
            acc[r][2] += a * w4.z; acc[r][3] += a * w4.w;
        }
    }
#pragma unroll
    for (int r = 0; r < 4; r++) {
        int node = base + 4 * ty + r;
        if (node < N) {
            HF2 u;
            u.h2[0] = __floats2half2_rn(acc[r][0], acc[r][1]);
            u.h2[1] = __floats2half2_rn(acc[r][2], acc[r][3]);
            *(float2*)(out + (size_t)node * 64 + 4 * tx) = u.f2;
        }
    }
}

// sum nb per-block partials (each 128 floats) into stats[128].
__global__ __launch_bounds__(64) void reduce_stats_kernel(
    const float* __restrict__ partials, float* __restrict__ stats, int nb)
{
    int c = blockIdx.x;
    int lane = threadIdx.x;
    float s = 0.f;
    for (int i = lane; i < nb; i += 64)
        s += partials[(size_t)i * 128 + c];
#pragma unroll
    for (int off = 32; off > 0; off >>= 1)
        s += __shfl_down(s, off, 64);
    if (lane == 0) stats[c] = s;
}

// Fused GIN layer. hin fp16, N+1 rows (row N = zeros). 64 nodes per block.
// ELL has N+1 rows; row N and all slots >= deg are 0xFFFF (clamped to N).
template <bool FIRST>
__global__ __launch_bounds__(256) void layer_kernel(
    const __half* __restrict__ hin, const unsigned short* __restrict__ ell,
    const int* __restrict__ deg,
    const float* __restrict__ statsPrev, const float* __restrict__ gamma, const float* __restrict__ beta,
    const float* __restrict__ bias0,
    const float* __restrict__ W1, const float* __restrict__ b1,
    const float* __restrict__ W2, const float* __restrict__ b2,
    __half* __restrict__ hout, float* __restrict__ statsPart)
{
    __shared__ float sV[64 * 68];   // stride 68
    __shared__ float sStat[128];

    int tid = threadIdx.x, lane = tid & 63, wv = tid >> 6;
    if (tid < 128) sStat[tid] = 0.f;

    int base = blockIdx.x * 64;
    int n8 = lane >> 3, f = lane & 7;   // node-sub (8), feature-oct (8)

    // per-lane channel oct f*8..f*8+7 epilogue params
    float sc[8], sh[8], b0[8];
    if constexpr (FIRST) {
#pragma unroll
        for (int q = 0; q < 2; q++) {
            float4 b4 = ld4(bias0 + 8 * f + 4 * q);
            b0[4 * q + 0] = b4.x; b0[4 * q + 1] = b4.y;
            b0[4 * q + 2] = b4.z; b0[4 * q + 3] = b4.w;
        }
    } else {
#pragma unroll
        for (int q = 0; q < 2; q++) {
            float4 s1 = ld4(statsPrev + 8 * f + 4 * q);
            float4 s2 = ld4(statsPrev + 64 + 8 * f + 4 * q);
            float4 g4 = ld4(gamma + 8 * f + 4 * q);
            float4 be4 = ld4(beta + 8 * f + 4 * q);
            float m[4] = { s1.x / N, s1.y / N, s1.z / N, s1.w / N };
            float v2[4] = { s2.x / N, s2.y / N, s2.z / N, s2.w / N };
            float gg[4] = { g4.x, g4.y, g4.z, g4.w };
            float bb4[4] = { be4.x, be4.y, be4.z, be4.w };
#pragma unroll
            for (int i = 0; i < 4; i++) {
                float s = gg[i] * rsqrtf(v2[i] - m[i] * m[i] + BN_EPS);
                sc[4 * q + i] = s;
                sh[4 * q + i] = bb4[i] - m[i] * s;
            }
        }
    }

    // ---- phase A: merged 2-deep gather; lane owns nodeA (slots 0-7) and nodeB (8-15) ----
    {
        int nodeA = base + wv * 16 + n8;
        int nodeB = nodeA + 8;
        int ndA = (nodeA < N) ? nodeA : N;
        int ndB = (nodeB < N) ? nodeB : N;
        int dgA = (nodeA < N) ? deg[nodeA] : 0;
        int dgB = (nodeB < N) ? deg[nodeB] : 0;
        int pA = (min(dgA, MAXDEG) + 7) & ~7;
        int pB = (min(dgB, MAXDEG) + 7) & ~7;
        int pm = max(pA, pB);
        const unsigned short* rowA = ell + (size_t)ndA * MAXDEG;
        const unsigned short* rowB = ell + (size_t)ndB * MAXDEG;

        __half2 apA[4][4], apB[4][4];
        __half2 z2 = __half2(__float2half(0.f), __float2half(0.f));
#pragma unroll
        for (int r = 0; r < 4; r++)
#pragma unroll
            for (int k = 0; k < 4; k++) { apA[r][k] = z2; apB[r][k] = z2; }

        float4 rownA = ld4((const float*)(hin + (size_t)ndA * 64 + 8 * f));
        float4 rownB = ld4((const float*)(hin + (size_t)ndB * 64 + 8 * f));

        for (int j = 0; j < pm; j += 8) {
            uint4 ivA = *(const uint4*)(rowA + j);
            uint4 ivB = *(const uint4*)(rowB + j);
            int a0 = min((int)(ivA.x & 0xFFFFu), N), a1 = min((int)(ivA.x >> 16), N);
            int a2 = min((int)(ivA.y & 0xFFFFu), N), a3 = min((int)(ivA.y >> 16), N);
            int a4 = min((int)(ivA.z & 0xFFFFu), N), a5 = min((int)(ivA.z >> 16), N);
            int a6 = min((int)(ivA.w & 0xFFFFu), N), a7 = min((int)(ivA.w >> 16), N);
            int b0i = min((int)(ivB.x & 0xFFFFu), N), b1i = min((int)(ivB.x >> 16), N);
            int b2i = min((int)(ivB.y & 0xFFFFu), N), b3i = min((int)(ivB.y >> 16), N);
            int b4i = min((int)(ivB.z & 0xFFFFu), N), b5i = min((int)(ivB.z >> 16), N);
            int b6i = min((int)(ivB.w & 0xFFFFu), N), b7i = min((int)(ivB.w >> 16), N);
            float4 rA0 = ld4((const float*)(hin + (size_t)a0 * 64 + 8 * f));
            float4 rA1 = ld4((const float*)(hin + (size_t)a1 * 64 + 8 * f));
            float4 rA2 = ld4((const float*)(hin + (size_t)a2 * 64 + 8 * f));
            float4 rA3 = ld4((const float*)(hin + (size_t)a3 * 64 + 8 * f));
            float4 rA4 = ld4((const float*)(hin + (size_t)a4 * 64 + 8 * f));
            float4 rA5 = ld4((const float*)(hin + (size_t)a5 * 64 + 8 * f));
            float4 rA6 = ld4((const float*)(hin + (size_t)a6 * 64 + 8 * f));
            float4 rA7 = ld4((const float*)(hin + (size_t)a7 * 64 + 8 * f));
            float4 rB0 = ld4((const float*)(hin + (size_t)b0i * 64 + 8 * f));
            float4 rB1 = ld4((const float*)(hin + (size_t)b1i * 64 + 8 * f));
            float4 rB2 = ld4((const float*)(hin + (size_t)b2i * 64 + 8 * f));
            float4 rB3 = ld4((const float*)(hin + (size_t)b3i * 64 + 8 * f));
            float4 rB4 = ld4((const float*)(hin + (size_t)b4i * 64 + 8 * f));
            float4 rB5 = ld4((const float*)(hin + (size_t)b5i * 64 + 8 * f));
            float4 rB6 = ld4((const float*)(hin + (size_t)b6i * 64 + 8 * f));
            float4 rB7 = ld4((const float*)(hin + (size_t)b7i * 64 + 8 * f));
            const __half2* hA0 = (const __half2*)&rA0; const __half2* hA1 = (const __half2*)&rA1;
            const __half2* hA2 = (const __half2*)&rA2; const __half2* hA3 = (const __half2*)&rA3;
            const __half2* hA4 = (const __half2*)&rA4; const __half2* hA5 = (const __half2*)&rA5;
            const __half2* hA6 = (const __half2*)&rA6; const __half2* hA7 = (const __half2*)&rA7;
            const __half2* hB0 = (const __half2*)&rB0; const __half2* hB1 = (const __half2*)&rB1;
            const __half2* hB2 = (const __half2*)&rB2; const __half2* hB3 = (const __half2*)&rB3;
            const __half2* hB4 = (const __half2*)&rB4; const __half2* hB5 = (const __half2*)&rB5;
            const __half2* hB6 = (const __half2*)&rB6; const __half2* hB7 = (const __half2*)&rB7;
#pragma unroll
            for (int k = 0; k < 4; k++) {
                apA[0][k] = __hadd2(apA[0][k], __hadd2(hA0[k], hA4[k]));
                apA[1][k] = __hadd2(apA[1][k], __hadd2(hA1[k], hA5[k]));
                apA[2][k] = __hadd2(apA[2][k], __hadd2(hA2[k], hA6[k]));
                apA[3][k] = __hadd2(apA[3][k], __hadd2(hA3[k], hA7[k]));
                apB[0][k] = __hadd2(apB[0][k], __hadd2(hB0[k], hB4[k]));
                apB[1][k] = __hadd2(apB[1][k], __hadd2(hB1[k], hB5[k]));
                apB[2][k] = __hadd2(apB[2][k], __hadd2(hB2[k], hB6[k]));
                apB[3][k] = __hadd2(apB[3][k], __hadd2(hB3[k], hB7[k]));
            }
        }

        // epilogue: fp32 combine of partials + own row, per node
        const __half2* hoA = (const __half2*)&rownA;
        const __half2* hoB = (const __half2*)&rownB;
        float vA[8], vB[8];
#pragma unroll
        for (int k = 0; k < 4; k++) {
            float2 sA = __half22float2(hoA[k]);
            float2 sB = __half22float2(hoB[k]);
#pragma unroll
            for (int r = 0; r < 4; r++) {
                float2 fa = __half22float2(apA[r][k]);
                float2 fb = __half22float2(apB[r][k]);
                sA.x += fa.x; sA.y += fa.y;
                sB.x += fb.x; sB.y += fb.y;
            }
            if constexpr (FIRST) {
                vA[2 * k]     = fmaxf(sA.x + b0[2 * k], 0.f);
                vA[2 * k + 1] = fmaxf(sA.y + b0[2 * k + 1], 0.f);
                vB[2 * k]     = fmaxf(sB.x + b0[2 * k], 0.f);
                vB[2 * k + 1] = fmaxf(sB.y + b0[2 * k + 1], 0.f);
            } else {
                float dshA = (float)(1 + dgA);
                float dshB = (float)(1 + dgB);
                vA[2 * k]     = sc[2 * k] * sA.x + dshA * sh[2 * k];
                vA[2 * k + 1] = sc[2 * k + 1] * sA.y + dshA * sh[2 * k + 1];
                vB[2 * k]     = sc[2 * k] * sB.x + dshB * sh[2 * k];
                vB[2 * k + 1] = sc[2 * k + 1] * sB.y + dshB * sh[2 * k + 1];
            }
        }
        int ridxA = wv * 16 + n8;
        int ridxB = wv * 16 + 8 + n8;
        st4(sV + ridxA * 68 + 8 * f,     make_float4(vA[0], vA[1], vA[2], vA[3]));
        st4(sV + ridxA * 68 + 8 * f + 4, make_float4(vA[4], vA[5], vA[6], vA[7]));
        st4(sV + ridxB * 68 + 8 * f,     make_float4(vB[0], vB[1], vB[2], vB[3]));
        st4(sV + ridxB * 68 + 8 * f + 4, make_float4(vB[4], vB[5], vB[6], vB[7]));
    }
    __syncthreads();

    int ty = tid >> 4, tx = tid & 15;

    if constexpr (!FIRST) {
        // ---- phase B: H = relu(V @ W1 + b1), in-place into sV ----
        float acc[4][4];
#pragma unroll
        for (int cc = 0; cc < 4; cc++) {
            float b = b1[4 * tx + cc];
            acc[0][cc] = b; acc[1][cc] = b; acc[2][cc] = b; acc[3][cc] = b;
        }
#pragma unroll 4
        for (int c = 0; c < 64; c++) {
            float4 w4 = ld4(W1 + c * 64 + 4 * tx);
#pragma unroll
            for (int r = 0; r < 4; r++) {
                float a = sV[(4 * ty + r) * 68 + c];
                acc[r][0] += a * w4.x; acc[r][1] += a * w4.y;
                acc[r][2] += a * w4.z; acc[r][3] += a * w4.w;
            }
        }
        __syncthreads();
#pragma unroll
        for (int r = 0; r < 4; r++)
            st4(sV + (4 * ty + r) * 68 + 4 * tx,
                make_float4(fmaxf(acc[r][0], 0.f), fmaxf(acc[r][1], 0.f),
                            fmaxf(acc[r][2], 0.f), fmaxf(acc[r][3], 0.f)));
        __syncthreads();
    }

    // ---- phase C: O = relu(V @ W2 + b2), store fp16, stats fp32 ----
    float acc[4][4];
#pragma unroll
    for (int cc = 0; cc < 4; cc++) {
        float b = b2[4 * tx + cc];
        acc[0][cc] = b; acc[1][cc] = b; acc[2][cc] = b; acc[3][cc] = b;
    }
#pragma unroll 4
    for (int c = 0; c < 64; c++) {
        float4 w4 = ld4(W2 + c * 64 + 4 * tx);
#pragma unroll
        for (int r = 0; r < 4; r++) {
            float a = sV[(4 * ty + r) * 68 + c];
            acc[r][0] += a * w4.x; acc[r][1] += a * w4.y;
            acc[r][2] += a * w4.z; acc[r][3] += a * w4.w;
        }
    }
#pragma unroll
    for (int r = 0; r < 4; r++) {
        int node = base + 4 * ty + r;
        if (node < N) {
            acc[r][0] = fmaxf(acc[r][0], 0.f); acc[r][1] = fmaxf(acc[r][1], 0.f);
            acc[r][2] = fmaxf(acc[r][2], 0.f); acc[r][3] = fmaxf(acc[r][3], 0.f);
            HF2 u;
            u.h2[0] = __floats2half2_rn(acc[r][0], acc[r][1]);
            u.h2[1] = __floats2half2_rn(acc[r][2], acc[r][3]);
            *(float2*)(hout + (size_t)node * 64 + 4 * tx) = u.f2;
        } else {
            acc[r][0] = acc[r][1] = acc[r][2] = acc[r][3] = 0.f;
        }
    }
#pragma unroll
    for (int cc = 0; cc < 4; cc++) {
        float s = 0.f, q = 0.f;
#pragma unroll
        for (int r = 0; r < 4; r++) { s += acc[r][cc]; q += acc[r][cc] * acc[r][cc]; }
        atomicAdd(&sStat[4 * tx + cc], s);
        atomicAdd(&sStat[64 + 4 * tx + cc], q);
    }
    __syncthreads();
    if (tid < 128) statsPart[(size_t)blockIdx.x * 128 + tid] = sStat[tid];
}

// pooled[g] = scale*sum_{n in g} h[n] + cnt*shift; z=relu(p@fc1+b1); z@fc2+b2; log_softmax
// Vectorized: 8 lanes x float4 (16B) cover one 128B row; 32 rows/iteration.
__global__ __launch_bounds__(256) void pool_head_kernel(
    const __half* __restrict__ h, const int* __restrict__ batch,
    const float* __restrict__ stats, const float* __restrict__ gamma, const float* __restrict__ beta,
    const float* __restrict__ fc1w, const float* __restrict__ fc1b,
    const float* __restrict__ fc2w, const float* __restrict__ fc2b,
    float* __restrict__ out)
{
    __shared__ float red[32][65];
    __shared__ float sp[64];
    __shared__ float sz[64];
    __shared__ float so[10];

    int tid = threadIdx.x;
    int g = blockIdx.x;

    int start, end;
    {
        int lo = 0, hi = N;
        while (lo < hi) { int mid = (lo + hi) >> 1; if (batch[mid] < g) lo = mid + 1; else hi = mid; }
        start = lo;
        lo = start; hi = N;
        while (lo < hi) { int mid = (lo + hi) >> 1; if (batch[mid] < g + 1) lo = mid + 1; else hi = mid; }
        end = lo;
    }

    int q = tid >> 3, sub = tid & 7;
    float a[8];
#pragma unroll
    for (int k = 0; k < 8; k++) a[k] = 0.f;

    for (int node = start + q; node < end; node += 32) {
        float4 raw = ld4((const float*)(h + (size_t)node * 64 + 8 * sub));
        const __half2* hh = (const __half2*)&raw;
#pragma unroll
        for (int k = 0; k < 4; k++) {
            float2 f2 = __half22float2(hh[k]);
            a[2 * k] += f2.x; a[2 * k + 1] += f2.y;
        }
    }
#pragma unroll
    for (int k = 0; k < 8; k++) red[q][8 * sub + k] = a[k];
    __syncthreads();

    if (tid < 64) {
        float t = 0.f;
#pragma unroll
        for (int qq = 0; qq < 32; qq++) t += red[qq][tid];
        float mean = stats[tid] * (1.f / N);
        float var  = stats[64 + tid] * (1.f / N) - mean * mean;
        float sc = gamma[tid] * rsqrtf(var + BN_EPS);
        float sh = beta[tid] - mean * sc;
        sp[tid] = sc * t + (float)(end - start) * sh;
    }
    __syncthreads();
    if (tid < 64) {
        float a1 = fc1b[tid];
#pragma unroll
        for (int c = 0; c < 64; c++) a1 += sp[c] * fc1w[c * 64 + tid];
        sz[tid] = fmaxf(a1, 0.f);
    }
    __syncthreads();
    if (tid < 10) {
        float z = fc2b[tid];
#pragma unroll
        for (int j = 0; j < 64; j++) z += sz[j] * fc2w[j * 10 + tid];
        so[tid] = z;
    }
    __syncthreads();
    if (tid < 10) {
        float m = -1e30f;
#pragma unroll
        for (int c = 0; c < 10; c++) m = fmaxf(m, so[c]);
        float s = 0.f;
#pragma unroll
        for (int c = 0; c < 10; c++) s += expf(so[c] - m);
        out[g * 10 + tid] = so[tid] - m - logf(s);
    }
}

extern "C" void kernel_launch(void* const* d_in, const int* in_sizes, int n_in,
                              void* d_out, int out_size, void* d_ws, size_t ws_size,
                              hipStream_t stream)
{
    const float* x    = (const float*)d_in[0];
    const int*   ei   = (const int*)  d_in[1];
    const int*   batch= (const int*)  d_in[2];
    const float* W1a  = (const float*)d_in[3];
    const float* b1a  = (const float*)d_in[4];
    const float* W1b  = (const float*)d_in[5];
    const float* b1b  = (const float*)d_in[6];
    const float* Wa   = (const float*)d_in[7];
    const float* ba   = (const float*)d_in[8];
    const float* Wb   = (const float*)d_in[9];
    const float* bb   = (const float*)d_in[10];
    const float* gammas = (const float*)d_in[11];
    const float* betas  = (const float*)d_in[12];
    const float* fc1w = (const float*)d_in[13];
    const float* fc1b = (const float*)d_in[14];
    const float* fc2w = (const float*)d_in[15];
    const float* fc2b = (const float*)d_in[16];
    float* out = (float*)d_out;

    // workspace carve (ell has N+1 rows; row N = all-0xFFFF sentinel)
    char* w = (char*)d_ws;
    int*            deg      = (int*)w;                      // @0          200,000 B (zeroed)
    float*          stats    = (float*)(w + 200704);         // @200,704    2,560 B
    unsigned short* ell      = (unsigned short*)(w + 203264);// @203,264    6,400,128 B (0xFF)
    __half*         bufA     = (__half*)(w + 6603392);       // @6,603,392  6,400,128 B
    __half*         bufB     = (__half*)(w + 13003520);      // @13,003,520 6,400,128 B
    float*          partials = (float*)(w + 19403648);       // @19,403,648 400,384 B

    hipMemsetAsync(deg, 0, 200000, stream);
    hipMemsetAsync(ell, 0xFF, 6400128, stream);
    hipMemsetAsync(bufA + (size_t)N * 64, 0, 128, stream);   // zero row N
    hipMemsetAsync(bufB + (size_t)N * 64, 0, 128, stream);

    count_fill_kernel<<<NPART * ((E + 255) / 256), 256, 0, stream>>>(ei, deg, ell);
    xw_kernel<<<(N + 63) / 64, 256, 0, stream>>>(x, W1a, bufA);

    int nb = (N + 63) / 64;

    layer_kernel<true><<<nb, 256, 0, stream>>>(
        bufA, ell, deg, nullptr, nullptr, nullptr, b1a,
        nullptr, nullptr, W1b, b1b, bufB, partials);
    reduce_stats_kernel<<<128, 64, 0, stream>>>(partials, stats, nb);

    layer_kernel<false><<<nb, 256, 0, stream>>>(
        bufB, ell, deg, stats, gammas, betas, nullptr,
        Wa, ba, Wb, bb, bufA, partials);
    reduce_stats_kernel<<<128, 64, 0, stream>>>(partials, stats + 128, nb);

    layer_kernel<false><<<nb, 256, 0, stream>>>(
        bufA, ell, deg, stats + 128, gammas + 64, betas + 64, nullptr,
        Wa + 4096, ba + 64, Wb + 4096, bb + 64, bufB, partials);
    reduce_stats_kernel<<<128, 64, 0, stream>>>(partials, stats + 256, nb);

    layer_kernel<false><<<nb, 256, 0, stream>>>(
        bufB, ell, deg, stats + 256, gammas + 128, betas + 128, nullptr,
        Wa + 8192, ba + 128, Wb + 8192, bb + 128, bufA, partials);
    reduce_stats_kernel<<<128, 64, 0, stream>>>(partials, stats + 384, nb);

    layer_kernel<false><<<nb, 256, 0, stream>>>(
        bufA, ell, deg, stats + 384, gammas + 192, betas + 192, nullptr,
        Wa + 12288, ba + 192, Wb + 12288, bb + 192, bufB, partials);
    reduce_stats_kernel<<<128, 64, 0, stream>>>(partials, stats + 512, nb);

    pool_head_kernel<<<G, 256, 0, stream>>>(
        bufB, batch, stats + 512, gammas + 256, betas + 256,
        fc1w, fc1b, fc2w, fc2b, out);
}